// Round 12
// baseline (365.159 us; speedup 1.0000x reference)
//
#include <hip/hip_runtime.h>
#include <math.h>

// Problem constants (fixed by setup_inputs)
#define NODES_TOT 7424      // 64 * 116
#define EDGES     237568    // NODES_TOT * 32
#define BATCH     64
#define NN        116
#define KDIM      7424      // FC K dim
#define N1        7424      // FC1 out
#define N2        13456     // FC2 out (116*116)
#define NV        6670      // unique i<j pairs
#define NVP       6720      // NV rounded to 64
#define NKB2      58        // KDIM / 128 k-steps (BK=128)
#define KSPLIT    8

typedef __attribute__((ext_vector_type(8))) short bf16x8;
typedef __attribute__((ext_vector_type(4))) float f32x4;
typedef __attribute__((ext_vector_type(4))) short s16x4;

__device__ __forceinline__ float mish_f(float v) {
    float sp = fmaxf(v, 0.0f) + log1pf(expf(-fabsf(v)));
    return v * tanhf(sp);
}

__device__ __forceinline__ unsigned short bf_rne(float f) {
    unsigned u = __float_as_uint(f);
    u += 0x7fffu + ((u >> 16) & 1u);
    return (unsigned short)(u >> 16);
}

__device__ __forceinline__ void gload_lds16(const void* g, void* l) {
    __builtin_amdgcn_global_load_lds(
        (const __attribute__((address_space(1))) void*)g,
        (__attribute__((address_space(3))) void*)l, 16, 0, 0);
}

__device__ __forceinline__ f32x4 ntload4(const float* p) {
    return __builtin_nontemporal_load((const f32x4*)p);
}

// ---------- small utility ----------
__global__ void zero_kernel(int* __restrict__ p, int n) {
    int i = blockIdx.x * 256 + threadIdx.x;
    if (i < n) p[i] = 0;
}

// ---------- CSR build ----------
__global__ void hist_kernel(const int* __restrict__ dst, int* __restrict__ hist) {
    int e = blockIdx.x * 256 + threadIdx.x;
    if (e < EDGES) atomicAdd(&hist[dst[e]], 1);
}

__global__ void scan_kernel(const int* __restrict__ hist, int* __restrict__ row_start,
                            int* __restrict__ cursor) {
    __shared__ int s[1024];
    int t = threadIdx.x;
    int base = t * 8;
    int loc[8];
    int sum = 0;
    #pragma unroll
    for (int c = 0; c < 8; ++c) {
        int idx = base + c;
        int v = (idx < NODES_TOT) ? hist[idx] : 0;
        loc[c] = sum;
        sum += v;
    }
    s[t] = sum;
    __syncthreads();
    for (int off = 1; off < 1024; off <<= 1) {
        int v = (t >= off) ? s[t - off] : 0;
        __syncthreads();
        s[t] += v;
        __syncthreads();
    }
    int excl = s[t] - sum;
    #pragma unroll
    for (int c = 0; c < 8; ++c) {
        int idx = base + c;
        if (idx < NODES_TOT) {
            int r = excl + loc[c];
            row_start[idx] = r;
            cursor[idx] = r;
        }
    }
}

__global__ void csr_fill_kernel(const int* __restrict__ src, const int* __restrict__ dst,
                                int* __restrict__ cursor, int* __restrict__ csr_src) {
    int e = blockIdx.x * 256 + threadIdx.x;
    if (e < EDGES) {
        int p = atomicAdd(&cursor[dst[e]], 1);
        csr_src[p] = src[e];
    }
}

// ---------- fused mean-aggregate + SAGE linear + mish ----------
template <bool BF>
__global__ void __launch_bounds__(256) conv_kernel(
        const float* __restrict__ x, const int* __restrict__ csr_src,
        const int* __restrict__ row_start, const int* __restrict__ deg_arr,
        const float* __restrict__ w_l, const float* __restrict__ b_l,
        const float* __restrict__ w_r, void* __restrict__ h_out_v) {
    __shared__ float wlT[64 * 64];   // [k][f]
    __shared__ float wrT[64 * 64];   // [k][f]
    __shared__ float mv[4][64];
    __shared__ float xv[4][64];
    int t = threadIdx.x;
    for (int i = 0; i < 16; ++i) {
        int idx = t + i * 256;
        int f = idx >> 6, k = idx & 63;
        wlT[k * 64 + f] = w_l[idx];
        wrT[k * 64 + f] = w_r[idx];
    }
    int g = t >> 6, f = t & 63;
    __syncthreads();
    for (int nb = blockIdx.x * 4; nb < NODES_TOT; nb += gridDim.x * 4) {
        int node = nb + g;
        int deg = deg_arr[node];
        int rs = row_start[node];
        float sum = 0.f;
        for (int e = 0; e < deg; ++e) {
            int s = csr_src[rs + e];
            sum += x[s * 64 + f];
        }
        float mean = sum / (float)max(deg, 1);
        mv[g][f] = mean;
        xv[g][f] = x[node * 64 + f];
        __syncthreads();
        float o = b_l[f];
        #pragma unroll
        for (int k = 0; k < 64; ++k) {
            o = fmaf(mv[g][k], wlT[k * 64 + f], o);
            o = fmaf(xv[g][k], wrT[k * 64 + f], o);
        }
        float m = mish_f(o);
        if (BF) ((unsigned short*)h_out_v)[node * 64 + f] = bf_rne(m);
        else    ((float*)h_out_v)[node * 64 + f] = m;
        __syncthreads();
    }
}

// ---------- pack1: fc1_w fp32 -> bf16 (pure sequential stream, nt reads) ----------
__global__ void pack1_kernel(const float* __restrict__ W, unsigned short* __restrict__ Wb) {
    const int total = (N1 * KDIM) / 4;    // f32x4 count
    int stride = gridDim.x * 256;
    for (int i = blockIdx.x * 256 + threadIdx.x; i < total; i += stride) {
        f32x4 v = ntload4(W + (size_t)i * 4);
        s16x4 o;
        #pragma unroll
        for (int j = 0; j < 4; ++j) o[j] = (short)bf_rne(v[j]);
        *(s16x4*)(Wb + (size_t)i * 4) = o;
    }
}

// ---------- pack2: symmetrized V[p] = bf16(0.5*(w[i*NN+j] + w[j*NN+i])), p over i<j ----
__global__ void __launch_bounds__(256) pack2_kernel(
        const float* __restrict__ W, const float* __restrict__ bvec,
        unsigned short* __restrict__ V, float* __restrict__ bs) {
    int p = blockIdx.x;
    // p -> (i, j), i<j (wave-uniform scalar loop, <=115 iters)
    int i = 0, rem = p;
    while (rem >= NN - 1 - i) { rem -= NN - 1 - i; ++i; }
    int j = i + 1 + rem;
    const float* r0 = W + (size_t)(i * NN + j) * KDIM;
    const float* r1 = W + (size_t)(j * NN + i) * KDIM;
    unsigned short* vp = V + (size_t)p * KDIM;
    int t = threadIdx.x;
    #pragma unroll
    for (int c = 0; c < 8; ++c) {
        int idx = c * 256 + t;               // f32x4 index, < 1856
        if (idx < KDIM / 4) {
            f32x4 a = ntload4(r0 + idx * 4);
            f32x4 b = ntload4(r1 + idx * 4);
            s16x4 o;
            #pragma unroll
            for (int e = 0; e < 4; ++e) o[e] = (short)bf_rne(0.5f * (a[e] + b[e]));
            *(s16x4*)(vp + idx * 4) = o;
        }
    }
    if (t == 0) bs[p] = 0.5f * (bvec[i * NN + j] + bvec[j * NN + i]);
}

// ---------- DMA-staged bf16xbf16 MFMA GEMM, BK=128, dbuf, counted vmcnt ----------
// Cp[by][64][N] = A[64][Ksl] * Wb[rows][Ksl]^T, both operands bf16 in HBM/L3.
// R6-verified swizzle (granule ^= row&7) on both operands, treated as 2 k-halves
// of 64. 8 DMA loads/wave/step; WAIT8 keeps next step's 8 in flight across barriers.
// NOTE: ISSUE takes a LOCAL 0-based step (kb0 is baked into wsrcp/asrcp).
__global__ void __launch_bounds__(256) gemm_bw(
        const unsigned short* __restrict__ Abf, const unsigned short* __restrict__ Wb,
        float* __restrict__ Cp, int N, int NROWS) {
    __shared__ __align__(16) unsigned short Wlds[2][2][4096];  // [buf][khalf][64r x 64k]
    __shared__ __align__(16) unsigned short Alds[2][2][4096];
    int t = threadIdx.x;
    int bx = blockIdx.x, by = blockIdx.y;
    int kb0 = (by * NKB2) / KSPLIT;
    int kb1 = ((by + 1) * NKB2) / KSPLIT;
    int S = kb1 - kb0;                 // 7 or 8
    int n0 = bx * 64;
    int wv = t >> 6, l = t & 63, l15 = l & 15, hi = l >> 4;

    // staging sources: 2 chunks per operand per k-half (R6 A-pattern, verified)
    const unsigned short* wsrcp[2];
    const unsigned short* asrcp[2];
    #pragma unroll
    for (int ii = 0; ii < 2; ++ii) {
        int rloc = wv * 16 + ii * 8 + (l >> 3);
        int wr = n0 + rloc; if (wr >= NROWS) wr = NROWS - 1;
        int g = (l & 7) ^ (rloc & 7);
        wsrcp[ii] = Wb  + (size_t)wr   * KDIM + (size_t)kb0 * 128 + g * 8;
        asrcp[ii] = Abf + (size_t)rloc * KDIM + (size_t)kb0 * 128 + g * 8;
    }

    f32x4 acc[4];
    #pragma unroll
    for (int g = 0; g < 4; ++g) acc[g] = (f32x4){0.f, 0.f, 0.f, 0.f};

#define ISSUE(step, buf) do {                                              \
        size_t ko = (size_t)(step) * 128;                                  \
        _Pragma("unroll")                                                  \
        for (int h = 0; h < 2; ++h) {                                      \
            _Pragma("unroll")                                              \
            for (int ii = 0; ii < 2; ++ii) {                               \
                gload_lds16(wsrcp[ii] + ko + h * 64,                       \
                            &Wlds[buf][h][(wv * 16 + ii * 8) * 64]);       \
                gload_lds16(asrcp[ii] + ko + h * 64,                       \
                            &Alds[buf][h][(wv * 16 + ii * 8) * 64]);       \
            }                                                              \
        }                                                                  \
    } while (0)

#define MFMAPH(buf) do {                                                   \
        _Pragma("unroll")                                                  \
        for (int h = 0; h < 2; ++h) {                                      \
            _Pragma("unroll")                                              \
            for (int s = 0; s < 2; ++s) {                                  \
                int fw = s * 4 + hi;                                       \
                int n = wv * 16 + l15;                                     \
                bf16x8 bh = *(const bf16x8*)&Wlds[buf][h][n * 64 + ((fw ^ (n & 7)) * 8)]; \
                _Pragma("unroll")                                          \
                for (int g = 0; g < 4; ++g) {                              \
                    int ar = g * 16 + l15;                                 \
                    bf16x8 av = *(const bf16x8*)&Alds[buf][h][ar * 64 + ((fw ^ (ar & 7)) * 8)]; \
                    acc[g] = __builtin_amdgcn_mfma_f32_16x16x32_bf16(av, bh, acc[g], 0, 0, 0); \
                }                                                          \
            }                                                              \
        }                                                                  \
    } while (0)

#define WAIT8()  asm volatile("s_waitcnt vmcnt(8)" ::: "memory")
#define WAIT0()  asm volatile("s_waitcnt vmcnt(0)" ::: "memory")
#define RBAR()   asm volatile("s_barrier" ::: "memory")
#define LBAR()   asm volatile("s_waitcnt lgkmcnt(0)\n\ts_barrier" ::: "memory")

    // prologue (S >= 7 always); LOCAL step indices
    ISSUE(0, 0);
    ISSUE(1, 1);
    int buf = 0;
    for (int s = 0; s < S; ++s) {
        if (s == S - 1) WAIT0(); else WAIT8();
        RBAR();                          // all waves' step-s loads landed
        MFMAPH(buf);
        LBAR();                          // all readers done with buf
        if (s + 2 < S) ISSUE(s + 2, buf);
        buf ^= 1;
    }

#undef ISSUE
#undef MFMAPH
#undef WAIT8
#undef WAIT0
#undef RBAR
#undef LBAR

    // store partials
    int gn = n0 + wv * 16 + l15;
    if (gn < N) {
        float* cp = Cp + (size_t)by * 64 * N;
        #pragma unroll
        for (int g = 0; g < 4; ++g)
            #pragma unroll
            for (int rr = 0; rr < 4; ++rr)
                cp[(size_t)(g * 16 + hi * 4 + rr) * N + gn] = acc[g][rr];
    }
}

// ---------- reduce partials + bias + mish + bf16 cast (FC1 epilogue) ----------
__global__ void reduce1_kernel(const float* __restrict__ Cp, const float* __restrict__ b,
                               unsigned short* __restrict__ A2) {
    int i4 = (blockIdx.x * 256 + threadIdx.x) * 4;
    if (i4 >= BATCH * N1) return;
    int n = i4 % N1;
    f32x4 acc = *(const f32x4*)(b + n);
    #pragma unroll
    for (int s = 0; s < KSPLIT; ++s)
        acc += *(const f32x4*)(Cp + (size_t)s * BATCH * N1 + i4);
    s16x4 o;
    #pragma unroll
    for (int j = 0; j < 4; ++j) o[j] = (short)bf_rne(mish_f(acc[j]));
    *(s16x4*)(A2 + i4) = o;
}

// ---------- reduce partials + sym-bias (FC2 epilogue, N=NVP padded) ----------
__global__ void reduce2_kernel(const float* __restrict__ Cp, const float* __restrict__ bs,
                               float* __restrict__ C2s) {
    int i4 = (blockIdx.x * 256 + threadIdx.x) * 4;
    if (i4 >= BATCH * NVP) return;
    int n = i4 % NVP;
    f32x4 acc = {0.f, 0.f, 0.f, 0.f};
    #pragma unroll
    for (int s = 0; s < KSPLIT; ++s)
        acc += *(const f32x4*)(Cp + (size_t)s * BATCH * NVP + i4);
    #pragma unroll
    for (int j = 0; j < 4; ++j)
        if (n + j < NV) acc[j] += bs[n + j];
    *(f32x4*)(C2s + i4) = acc;
}

// ---------- scatter symmetric output from pair-compressed C2s ----------
__global__ void sym_kernel(const float* __restrict__ C2s, float* __restrict__ out) {
    int tid = blockIdx.x * 256 + threadIdx.x;
    if (tid >= BATCH * NN * NN) return;
    int j = tid % NN;
    int r = tid / NN;
    int i = r % NN;
    int b = r / NN;
    float v;
    if (i == j) {
        v = 1.0f;
    } else {
        int lo = min(i, j), hj = max(i, j);
        int p = lo * (2 * NN - lo - 1) / 2 + (hj - lo - 1);
        v = C2s[(size_t)b * NVP + p];
    }
    out[tid] = v;
}

extern "C" void kernel_launch(void* const* d_in, const int* in_sizes, int n_in,
                              void* d_out, int out_size, void* d_ws, size_t ws_size,
                              hipStream_t stream) {
    const float* z     = (const float*)d_in[0];
    const int*   edge  = (const int*)d_in[1];
    const float* w1_l  = (const float*)d_in[3];
    const float* b1_l  = (const float*)d_in[4];
    const float* w1_r  = (const float*)d_in[5];
    const float* w2_l  = (const float*)d_in[6];
    const float* b2_l  = (const float*)d_in[7];
    const float* w2_r  = (const float*)d_in[8];
    const float* fc1_w = (const float*)d_in[9];
    const float* fc1_b = (const float*)d_in[10];
    const float* fc2_w = (const float*)d_in[11];
    const float* fc2_b = (const float*)d_in[12];
    float* out = (float*)d_out;

    char* ws = (char*)d_ws;
    size_t off = 0;
    auto alloc = [&](size_t bytes) {
        void* p = ws + off;
        off = (off + bytes + 255) & ~(size_t)255;
        return p;
    };
    int*            hist      = (int*)alloc(NODES_TOT * 4);
    int*            row_start = (int*)alloc(NODES_TOT * 4);
    int*            cursor    = (int*)alloc(NODES_TOT * 4);
    int*            csr_src   = (int*)alloc((size_t)EDGES * 4);
    float*          h1        = (float*)alloc((size_t)NODES_TOT * 64 * 4);
    unsigned short* A1        = (unsigned short*)alloc((size_t)NODES_TOT * 64 * 2);
    unsigned short* W1b       = (unsigned short*)alloc((size_t)N1 * KDIM * 2);
    unsigned short* Vb        = (unsigned short*)alloc((size_t)NVP * KDIM * 2);
    float*          bsym      = (float*)alloc((size_t)NV * 4);
    float*          Cp1       = (float*)alloc((size_t)KSPLIT * BATCH * N1 * 4);
    unsigned short* A2        = (unsigned short*)alloc((size_t)BATCH * N1 * 2);
    float*          Cp2       = (float*)alloc((size_t)KSPLIT * BATCH * NVP * 4);
    float*          C2s       = (float*)alloc((size_t)BATCH * NVP * 4);

    const int* src = edge;
    const int* dst = edge + EDGES;

    zero_kernel<<<(NODES_TOT + 255) / 256, 256, 0, stream>>>(hist, NODES_TOT);
    hist_kernel<<<(EDGES + 255) / 256, 256, 0, stream>>>(dst, hist);
    scan_kernel<<<1, 1024, 0, stream>>>(hist, row_start, cursor);
    csr_fill_kernel<<<(EDGES + 255) / 256, 256, 0, stream>>>(src, dst, cursor, csr_src);

    conv_kernel<false><<<928, 256, 0, stream>>>(z, csr_src, row_start, hist, w1_l, b1_l, w1_r, h1);
    conv_kernel<true><<<928, 256, 0, stream>>>(h1, csr_src, row_start, hist, w2_l, b2_l, w2_r, A1);

    // FC1: pack fp32->bf16 (sequential stream), then bf16 GEMM (W L3-hot)
    pack1_kernel<<<2048, 256, 0, stream>>>(fc1_w, W1b);
    gemm_bw<<<dim3(N1 / 64, KSPLIT), 256, 0, stream>>>(A1, W1b, Cp1, N1, N1);
    reduce1_kernel<<<(BATCH * N1 / 4 + 255) / 256, 256, 0, stream>>>(Cp1, fc1_b, A2);

    // FC2: symmetrized pair-compressed bf16 pack (halves mandatory bytes), then GEMM
    pack2_kernel<<<NV, 256, 0, stream>>>(fc2_w, fc2_b, Vb, bsym);
    gemm_bw<<<dim3(NVP / 64, KSPLIT), 256, 0, stream>>>(A2, Vb, Cp2, NVP, NV);
    reduce2_kernel<<<(BATCH * NVP / 4 + 255) / 256, 256, 0, stream>>>(Cp2, bsym, C2s);

    sym_kernel<<<(BATCH * NN * NN + 255) / 256, 256, 0, stream>>>(C2s, out);
}

// Round 13
// 317.204 us; speedup vs baseline: 1.1512x; 1.1512x over previous
//
#include <hip/hip_runtime.h>
#include <math.h>

// Problem constants (fixed by setup_inputs)
#define NODES_TOT 7424      // 64 * 116
#define EDGES     237568    // NODES_TOT * 32
#define BATCH     64
#define NN        116
#define KDIM      7424      // FC K dim
#define N1        7424      // FC1 out
#define N2        13456     // FC2 out (116*116)
#define KSPLIT    4         // both GEMMs: 116 sub-steps / 4 = 29 per block

typedef __attribute__((ext_vector_type(8))) short bf16x8;
typedef __attribute__((ext_vector_type(4))) float f32x4;
typedef __attribute__((ext_vector_type(4))) short s16x4;

__device__ __forceinline__ float mish_f(float v) {
    float sp = fmaxf(v, 0.0f) + log1pf(expf(-fabsf(v)));
    return v * tanhf(sp);
}

__device__ __forceinline__ unsigned short bf_rne(float f) {
    unsigned u = __float_as_uint(f);
    u += 0x7fffu + ((u >> 16) & 1u);
    return (unsigned short)(u >> 16);
}

// ---------- small utility ----------
__global__ void zero_kernel(int* __restrict__ p, int n) {
    int i = blockIdx.x * 256 + threadIdx.x;
    if (i < n) p[i] = 0;
}

// ---------- CSR build ----------
__global__ void hist_kernel(const int* __restrict__ dst, int* __restrict__ hist) {
    int e = blockIdx.x * 256 + threadIdx.x;
    if (e < EDGES) atomicAdd(&hist[dst[e]], 1);
}

__global__ void scan_kernel(const int* __restrict__ hist, int* __restrict__ row_start,
                            int* __restrict__ cursor) {
    __shared__ int s[1024];
    int t = threadIdx.x;
    int base = t * 8;
    int loc[8];
    int sum = 0;
    #pragma unroll
    for (int c = 0; c < 8; ++c) {
        int idx = base + c;
        int v = (idx < NODES_TOT) ? hist[idx] : 0;
        loc[c] = sum;
        sum += v;
    }
    s[t] = sum;
    __syncthreads();
    for (int off = 1; off < 1024; off <<= 1) {
        int v = (t >= off) ? s[t - off] : 0;
        __syncthreads();
        s[t] += v;
        __syncthreads();
    }
    int excl = s[t] - sum;
    #pragma unroll
    for (int c = 0; c < 8; ++c) {
        int idx = base + c;
        if (idx < NODES_TOT) {
            int r = excl + loc[c];
            row_start[idx] = r;
            cursor[idx] = r;
        }
    }
}

__global__ void csr_fill_kernel(const int* __restrict__ src, const int* __restrict__ dst,
                                int* __restrict__ cursor, int* __restrict__ csr_src) {
    int e = blockIdx.x * 256 + threadIdx.x;
    if (e < EDGES) {
        int p = atomicAdd(&cursor[dst[e]], 1);
        csr_src[p] = src[e];
    }
}

// ---------- fused mean-aggregate + SAGE linear + mish ----------
template <bool BF>
__global__ void __launch_bounds__(256) conv_kernel(
        const float* __restrict__ x, const int* __restrict__ csr_src,
        const int* __restrict__ row_start, const int* __restrict__ deg_arr,
        const float* __restrict__ w_l, const float* __restrict__ b_l,
        const float* __restrict__ w_r, void* __restrict__ h_out_v) {
    __shared__ float wlT[64 * 64];   // [k][f]
    __shared__ float wrT[64 * 64];   // [k][f]
    __shared__ float mv[4][64];
    __shared__ float xv[4][64];
    int t = threadIdx.x;
    for (int i = 0; i < 16; ++i) {
        int idx = t + i * 256;
        int f = idx >> 6, k = idx & 63;
        wlT[k * 64 + f] = w_l[idx];
        wrT[k * 64 + f] = w_r[idx];
    }
    int g = t >> 6, f = t & 63;
    __syncthreads();
    for (int nb = blockIdx.x * 4; nb < NODES_TOT; nb += gridDim.x * 4) {
        int node = nb + g;
        int deg = deg_arr[node];
        int rs = row_start[node];
        float sum = 0.f;
        for (int e = 0; e < deg; ++e) {
            int s = csr_src[rs + e];
            sum += x[s * 64 + f];
        }
        float mean = sum / (float)max(deg, 1);
        mv[g][f] = mean;
        xv[g][f] = x[node * 64 + f];
        __syncthreads();
        float o = b_l[f];
        #pragma unroll
        for (int k = 0; k < 64; ++k) {
            o = fmaf(mv[g][k], wlT[k * 64 + f], o);
            o = fmaf(xv[g][k], wrT[k * 64 + f], o);
        }
        float m = mish_f(o);
        if (BF) ((unsigned short*)h_out_v)[node * 64 + f] = bf_rne(m);
        else    ((float*)h_out_v)[node * 64 + f] = m;
        __syncthreads();
    }
}

// ---------- burst-fetch bf16-MFMA GEMM (champion R8 structure) ----------
// Cp[by][64][N] = A[64][29*64] * W[Ntile][29*64]^T, sub-step BK=64, S=29 static.
// W fetched in 2-sub-step register bursts (8 x f32x4/thread = 512 B contiguous per
// W row per issue moment), two sets (wA/wB), 2-body flight. A staged reg->LDS.
// LDS dbuf, raw lgkmcnt(0)+s_barrier per body, no vmcnt drains.
__global__ void __launch_bounds__(256) gemm_burst(
        const unsigned short* __restrict__ Abf, const float* __restrict__ W,
        float* __restrict__ Cp, int N) {
    __shared__ __align__(16) short Wsh[2][4096];
    __shared__ __align__(16) short Ash[2][4096];
    int t = threadIdx.x;
    int bx = blockIdx.x, by = blockIdx.y;
    int n0 = bx * 64;
    // staging indices: row r = t>>2, quad q = t&3 (4 lanes cover one 64B line)
    int r = t >> 2, q = t & 3;
    int wr = n0 + r; if (wr >= N) wr = N - 1;
    const float*          wsrc = W   + (size_t)wr * KDIM + (size_t)by * 29 * 64 + q * 4;
    const unsigned short* asrc = Abf + (size_t)r  * KDIM + (size_t)by * 29 * 64 + q * 8;
    int fb = q >> 1, hf = q & 1;
    // compute indices
    int wv = t >> 6, l = t & 63, l15 = l & 15, hi = l >> 4;
    f32x4 acc[4];
    #pragma unroll
    for (int g = 0; g < 4; ++g) acc[g] = (f32x4){0.f, 0.f, 0.f, 0.f};

    f32x4 wA[8], wB[8];
    bf16x8 aEv[2], aOd[2];

#define IW2(dst, s) do {                                                  \
        dst[0] = *(const f32x4*)(wsrc + (s) * 64 + 0);                    \
        dst[1] = *(const f32x4*)(wsrc + (s) * 64 + 16);                   \
        dst[2] = *(const f32x4*)(wsrc + (s) * 64 + 32);                   \
        dst[3] = *(const f32x4*)(wsrc + (s) * 64 + 48);                   \
        dst[4] = *(const f32x4*)(wsrc + (s) * 64 + 64);                   \
        dst[5] = *(const f32x4*)(wsrc + (s) * 64 + 80);                   \
        dst[6] = *(const f32x4*)(wsrc + (s) * 64 + 96);                   \
        dst[7] = *(const f32x4*)(wsrc + (s) * 64 + 112);                  \
    } while (0)

#define IW1(dst, s) do {                                                  \
        dst[0] = *(const f32x4*)(wsrc + (s) * 64 + 0);                    \
        dst[1] = *(const f32x4*)(wsrc + (s) * 64 + 16);                   \
        dst[2] = *(const f32x4*)(wsrc + (s) * 64 + 32);                   \
        dst[3] = *(const f32x4*)(wsrc + (s) * 64 + 48);                   \
    } while (0)

#define IA(dst, s) do {                                                   \
        dst[0] = *(const bf16x8*)(asrc + (s) * 64);                       \
        dst[1] = *(const bf16x8*)(asrc + (s) * 64 + 32);                  \
    } while (0)

    // convert 4 f32x4 (one sub-step's W for this thread) + write W,A to LDS buf b
#define CW(W0, W1, W2, W3, av, b) do {                                    \
        s16x4 cv0, cv1, cv2, cv3;                                         \
        _Pragma("unroll")                                                 \
        for (int j = 0; j < 4; ++j) {                                     \
            cv0[j] = (short)bf_rne(W0[j]);                                \
            cv1[j] = (short)bf_rne(W1[j]);                                \
            cv2[j] = (short)bf_rne(W2[j]);                                \
            cv3[j] = (short)bf_rne(W3[j]);                                \
        }                                                                 \
        *(s16x4*)&Wsh[b][((0 + fb) * 64 + r) * 8 + hf * 4] = cv0;         \
        *(s16x4*)&Wsh[b][((2 + fb) * 64 + r) * 8 + hf * 4] = cv1;         \
        *(s16x4*)&Wsh[b][((4 + fb) * 64 + r) * 8 + hf * 4] = cv2;         \
        *(s16x4*)&Wsh[b][((6 + fb) * 64 + r) * 8 + hf * 4] = cv3;         \
        *(bf16x8*)&Ash[b][(q * 64 + r) * 8] = av[0];                      \
        *(bf16x8*)&Ash[b][((q + 4) * 64 + r) * 8] = av[1];                \
    } while (0)

#define MFMAPH(b) do {                                                    \
        _Pragma("unroll")                                                 \
        for (int s = 0; s < 2; ++s) {                                     \
            int fw = s * 4 + hi;                                          \
            bf16x8 bh = *(const bf16x8*)&Wsh[b][(fw * 64 + wv * 16 + l15) * 8]; \
            _Pragma("unroll")                                             \
            for (int g = 0; g < 4; ++g) {                                 \
                bf16x8 avv = *(const bf16x8*)&Ash[b][(fw * 64 + g * 16 + l15) * 8]; \
                acc[g] = __builtin_amdgcn_mfma_f32_16x16x32_bf16(avv, bh, acc[g], 0, 0, 0); \
            }                                                             \
        }                                                                 \
    } while (0)

#define LBAR() asm volatile("s_waitcnt lgkmcnt(0)\n\ts_barrier" ::: "memory")

    // prologue: wA={0,1}, wB={2,3}; A 2-deep
    IW2(wA, 0);
    IW2(wB, 2);
    IA(aEv, 0);
    IA(aOd, 1);
    CW(wA[0], wA[1], wA[2], wA[3], aEv, 0);    // sub 0 -> buf0
    LBAR();

    for (int g = 0; g < 7; ++g) {
        int kb = g * 4;
        // body kb+0 (buf0)
        MFMAPH(0);
        CW(wA[4], wA[5], wA[6], wA[7], aOd, 1);    // sub kb+1 -> buf1
        IA(aEv, kb + 2);
        LBAR();
        // body kb+1 (buf1)
        if (g < 6) IW2(wA, kb + 4); else IW1(wA, 28);
        MFMAPH(1);
        CW(wB[0], wB[1], wB[2], wB[3], aEv, 0);    // sub kb+2 -> buf0
        IA(aOd, kb + 3);
        LBAR();
        // body kb+2 (buf0)
        MFMAPH(0);
        CW(wB[4], wB[5], wB[6], wB[7], aOd, 1);    // sub kb+3 -> buf1
        IA(aEv, kb + 4);
        LBAR();
        // body kb+3 (buf1)
        if (g < 6) IW2(wB, kb + 6);
        MFMAPH(1);
        CW(wA[0], wA[1], wA[2], wA[3], aEv, 0);    // sub kb+4 -> buf0
        if (g < 6) IA(aOd, kb + 5);
        LBAR();
    }
    MFMAPH(0);                                      // sub 28 (buf0)

#undef IW2
#undef IW1
#undef IA
#undef CW
#undef MFMAPH
#undef LBAR

    // store partials
    int gn = n0 + wv * 16 + l15;
    if (gn < N) {
        float* cp = Cp + (size_t)by * 64 * N;
        #pragma unroll
        for (int g = 0; g < 4; ++g)
            #pragma unroll
            for (int rr = 0; rr < 4; ++rr)
                cp[(size_t)(g * 16 + hi * 4 + rr) * N + gn] = acc[g][rr];
    }
}

// ---------- reduce partials + bias + mish + bf16 cast (FC1 epilogue) ----------
__global__ void reduce1_kernel(const float* __restrict__ Cp, const float* __restrict__ b,
                               unsigned short* __restrict__ A2) {
    int i4 = (blockIdx.x * 256 + threadIdx.x) * 4;
    if (i4 >= BATCH * N1) return;
    int n = i4 % N1;
    f32x4 acc = *(const f32x4*)(b + n);
    #pragma unroll
    for (int s = 0; s < KSPLIT; ++s)
        acc += *(const f32x4*)(Cp + (size_t)s * BATCH * N1 + i4);
    s16x4 o;
    #pragma unroll
    for (int j = 0; j < 4; ++j) o[j] = (short)bf_rne(mish_f(acc[j]));
    *(s16x4*)(A2 + i4) = o;
}

// ---------- reduce partials + bias (FC2 epilogue) ----------
__global__ void reduce2_kernel(const float* __restrict__ Cp, const float* __restrict__ b,
                               float* __restrict__ C2) {
    int i4 = (blockIdx.x * 256 + threadIdx.x) * 4;
    if (i4 >= BATCH * N2) return;
    int n = i4 % N2;
    f32x4 acc = *(const f32x4*)(b + n);
    #pragma unroll
    for (int s = 0; s < KSPLIT; ++s)
        acc += *(const f32x4*)(Cp + (size_t)s * BATCH * N2 + i4);
    *(f32x4*)(C2 + i4) = acc;
}

// ---------- symmetrize + unit diagonal (C2 L2-resident, bias pre-added) ----------
__global__ void sym_kernel(const float* __restrict__ C2, float* __restrict__ out) {
    int tid = blockIdx.x * 256 + threadIdx.x;
    if (tid >= BATCH * NN * NN) return;
    int j = tid % NN;
    int r = tid / NN;
    int i = r % NN;
    int b = r / NN;
    float v;
    if (i == j) {
        v = 1.0f;
    } else {
        v = 0.5f * (C2[(size_t)b * N2 + i * NN + j] + C2[(size_t)b * N2 + j * NN + i]);
    }
    out[tid] = v;
}

extern "C" void kernel_launch(void* const* d_in, const int* in_sizes, int n_in,
                              void* d_out, int out_size, void* d_ws, size_t ws_size,
                              hipStream_t stream) {
    const float* z     = (const float*)d_in[0];
    const int*   edge  = (const int*)d_in[1];
    const float* w1_l  = (const float*)d_in[3];
    const float* b1_l  = (const float*)d_in[4];
    const float* w1_r  = (const float*)d_in[5];
    const float* w2_l  = (const float*)d_in[6];
    const float* b2_l  = (const float*)d_in[7];
    const float* w2_r  = (const float*)d_in[8];
    const float* fc1_w = (const float*)d_in[9];
    const float* fc1_b = (const float*)d_in[10];
    const float* fc2_w = (const float*)d_in[11];
    const float* fc2_b = (const float*)d_in[12];
    float* out = (float*)d_out;

    char* ws = (char*)d_ws;
    size_t off = 0;
    auto alloc = [&](size_t bytes) {
        void* p = ws + off;
        off = (off + bytes + 255) & ~(size_t)255;
        return p;
    };
    int*            hist      = (int*)alloc(NODES_TOT * 4);
    int*            row_start = (int*)alloc(NODES_TOT * 4);
    int*            cursor    = (int*)alloc(NODES_TOT * 4);
    int*            csr_src   = (int*)alloc((size_t)EDGES * 4);
    float*          h1        = (float*)alloc((size_t)NODES_TOT * 64 * 4);
    unsigned short* A1        = (unsigned short*)alloc((size_t)NODES_TOT * 64 * 2);
    float*          Cp1       = (float*)alloc((size_t)KSPLIT * BATCH * N1 * 4);
    unsigned short* A2        = (unsigned short*)alloc((size_t)BATCH * N1 * 2);
    float*          Cp2       = (float*)alloc((size_t)KSPLIT * BATCH * N2 * 4);
    float*          C2        = (float*)alloc((size_t)BATCH * N2 * 4);

    const int* src = edge;
    const int* dst = edge + EDGES;

    zero_kernel<<<(NODES_TOT + 255) / 256, 256, 0, stream>>>(hist, NODES_TOT);
    hist_kernel<<<(EDGES + 255) / 256, 256, 0, stream>>>(dst, hist);
    scan_kernel<<<1, 1024, 0, stream>>>(hist, row_start, cursor);
    csr_fill_kernel<<<(EDGES + 255) / 256, 256, 0, stream>>>(src, dst, cursor, csr_src);

    conv_kernel<false><<<928, 256, 0, stream>>>(z, csr_src, row_start, hist, w1_l, b1_l, w1_r, h1);
    conv_kernel<true><<<928, 256, 0, stream>>>(h1, csr_src, row_start, hist, w2_l, b2_l, w2_r, A1);

    // FC1: 116 n-tiles x 4 k-splits (29 sub-steps each)
    gemm_burst<<<dim3(N1 / 64, KSPLIT), 256, 0, stream>>>(A1, fc1_w, Cp1, N1);
    reduce1_kernel<<<(BATCH * N1 / 4 + 255) / 256, 256, 0, stream>>>(Cp1, fc1_b, A2);

    // FC2: 211 n-tiles x 4 k-splits
    gemm_burst<<<dim3((N2 + 63) / 64, KSPLIT), 256, 0, stream>>>(A2, fc2_w, Cp2, N2);
    reduce2_kernel<<<(BATCH * N2 / 4 + 255) / 256, 256, 0, stream>>>(Cp2, fc2_b, C2);

    sym_kernel<<<(BATCH * NN * NN + 255) / 256, 256, 0, stream>>>(C2, out);
}